// Round 5
// baseline (1712.695 us; speedup 1.0000x reference)
//
#include <hip/hip_runtime.h>
#include <stdint.h>

// Problem dims
#define HDIM   1024
#define BDIM   128
#define TSTEPS 128
#define DDIM   256
#define ODIM   1024

// Workspace byte offsets
// stamps: 256 blocks x 64B line each (monotonic step counters)
#define WS_STAMP 0
#define WS_HBUF  16384                                 // ushort [2][128][1024]
#define WS_PBUF  (WS_HBUF + 2*BDIM*HDIM*2)             // float  [128][1024]
#define WS_WHHI  (WS_PBUF + BDIM*ODIM*4)               // ushort [4096][1024]
#define WS_WHLO  (WS_WHHI + 4*HDIM*HDIM*2)             // ushort [4096][1024]
#define WS_WXHI  (WS_WHLO + 4*HDIM*HDIM*2)             // ushort [4096][256]
#define WS_XT    (WS_WXHI + 4*HDIM*DDIM*2)             // ushort [128][128][256]

// LDS layout (rows padded: 1288*2B, 1032*2B; conflict-free b128 rotation)
#define SMEM_WHI_ROW 1288   // 1024 Wh_hi + 256 Wx_hi + 8 pad
#define SMEM_WLO_ROW 1032   // 1024 Wh_lo + 8 pad
#define SMEM_BYTES   (32*SMEM_WHI_ROW*2 + 32*SMEM_WLO_ROW*2 + 64*33*4)  // 156,928 B
#define SMEM_H_ROW   1032   // projection staging: 64 rows x 1032 u16 = 132,096 B (reuses smem)

typedef __attribute__((ext_vector_type(8))) short frag8;
typedef __attribute__((ext_vector_type(4))) float f32x4;

__device__ __forceinline__ unsigned short f2bf(float f) {
  union { float f; unsigned u; } v; v.f = f;
  unsigned r = v.u + 0x7fffu + ((v.u >> 16) & 1u);   // RNE
  return (unsigned short)(r >> 16);
}
__device__ __forceinline__ float bf2f(unsigned short h) {
  union { unsigned u; float f; } v; v.u = ((unsigned)h) << 16;
  return v.f;
}
__device__ __forceinline__ float sigm(float x) { return 1.f / (1.f + __expf(-x)); }
__device__ __forceinline__ float tanh_f(float x) {
  x = fminf(fmaxf(x, -20.f), 20.f);
  float e = __expf(2.f * x);
  return (e - 1.f) / (e + 1.f);
}

// Coherence idiom (gfx950, non-coherent per-XCD L2), NO fences/invalidates anywhere:
//  - producers: relaxed AGENT u32/f32 atomic stores (write-through to LLC; L2 never dirty)
//  - __syncthreads() drains vmcnt(0) -> stores complete at LLC before tid0's stamp store
//  - consumers: relaxed AGENT atomic loads (sc1, bypass L2 -> always see LLC-fresh data).
//    hbuf/pbuf therefore never live in L2 at all; xt/weights stay L2-warm (no inv storm).
__device__ __forceinline__ void st_agent_u32(unsigned* p, unsigned v) {
  __hip_atomic_store(p, v, __ATOMIC_RELAXED, __HIP_MEMORY_SCOPE_AGENT);
}
__device__ __forceinline__ void st_agent_f32(float* p, float v) {
  __hip_atomic_store(p, v, __ATOMIC_RELAXED, __HIP_MEMORY_SCOPE_AGENT);
}
__device__ __forceinline__ unsigned long long ld_agent_u64(const unsigned long long* p) {
  return __hip_atomic_load(p, __ATOMIC_RELAXED, __HIP_MEMORY_SCOPE_AGENT);
}
__device__ __forceinline__ unsigned ld_agent_u32(const unsigned* p) {
  return __hip_atomic_load(p, __ATOMIC_RELAXED, __HIP_MEMORY_SCOPE_AGENT);
}

// ---------------- prep: fp32 -> bf16 (hi/lo) reformat + x transpose ----------------
__global__ void prep_kernel(const float* __restrict__ Wh, const float* __restrict__ Wx,
                            const float* __restrict__ x, unsigned char* __restrict__ ws)
{
  unsigned short* whhi = (unsigned short*)(ws + WS_WHHI);
  unsigned short* whlo = (unsigned short*)(ws + WS_WHLO);
  unsigned short* wxhi = (unsigned short*)(ws + WS_WXHI);
  unsigned short* xt   = (unsigned short*)(ws + WS_XT);
  const int NWH = 4*HDIM*HDIM/4;       // 1,048,576 float4 items
  const int NWX = 4*HDIM*DDIM/4;       //   262,144
  const int NX  = BDIM*TSTEPS*DDIM/4;  // 1,048,576
  int stride = gridDim.x * blockDim.x;
  for (int i = blockIdx.x*blockDim.x + threadIdx.x; i < NWH+NWX+NX; i += stride) {
    if (i < NWH) {
      float4 w = ((const float4*)Wh)[i];
      ushort4 hi, lo;
      hi.x = f2bf(w.x); lo.x = f2bf(w.x - bf2f(hi.x));
      hi.y = f2bf(w.y); lo.y = f2bf(w.y - bf2f(hi.y));
      hi.z = f2bf(w.z); lo.z = f2bf(w.z - bf2f(hi.z));
      hi.w = f2bf(w.w); lo.w = f2bf(w.w - bf2f(hi.w));
      ((ushort4*)whhi)[i] = hi;
      ((ushort4*)whlo)[i] = lo;
    } else if (i < NWH + NWX) {
      int j = i - NWH;
      float4 w = ((const float4*)Wx)[j];
      ushort4 hi;
      hi.x = f2bf(w.x); hi.y = f2bf(w.y); hi.z = f2bf(w.z); hi.w = f2bf(w.w);
      ((ushort4*)wxhi)[j] = hi;
    } else {
      int j = i - NWH - NWX;           // x flat [b][t][dv], dv = float4 index
      int dv = j & 63;
      int t  = (j >> 6) & (TSTEPS - 1);
      int b  = j >> 13;
      float4 w = ((const float4*)x)[j];
      ushort4 hv;
      hv.x = f2bf(w.x); hv.y = f2bf(w.y); hv.z = f2bf(w.z); hv.w = f2bf(w.w);
      ((ushort4*)xt)[((size_t)t*BDIM + b)*64 + dv] = hv;   // xT[t][b][d]
    }
  }
}

// ---------------- persistent LSTM kernel (cooperative, 256 blocks x 256 thr) ----------------
// Block (mh = blockIdx&1, nsl = blockIdx>>1): batch rows [mh*64, +64), h-cols [nsl*8, +8)
// Sync: per-block monotonic stamp (own 64B line). Consumers wait wave-parallel: 128 lanes
// poll the 128 same-group stamps (exec-mask while loop) -> detect ~ 1 poll RT, no middleman.
__global__ void __launch_bounds__(256, 1)
lstm_main(const float* __restrict__ bx, const float* __restrict__ Wp,
          const float* __restrict__ bp, unsigned char* __restrict__ ws,
          float* __restrict__ out)
{
  extern __shared__ unsigned char smem[];
  unsigned short* sWhi = (unsigned short*)smem;                            // [32][1288]
  unsigned short* sWlo = (unsigned short*)(smem + 32*SMEM_WHI_ROW*2);      // [32][1032]
  float*          sG   = (float*)(smem + 32*SMEM_WHI_ROW*2 + 32*SMEM_WLO_ROW*2); // [64][33]

  unsigned*       stamp = (unsigned*)(ws + WS_STAMP);          // [256] x 16 dwords (64B)
  unsigned short* hbuf  = (unsigned short*)(ws + WS_HBUF);
  float*          pbuf  = (float*)(ws + WS_PBUF);
  const unsigned short* whhi = (const unsigned short*)(ws + WS_WHHI);
  const unsigned short* whlo = (const unsigned short*)(ws + WS_WHLO);
  const unsigned short* wxhi = (const unsigned short*)(ws + WS_WXHI);
  const unsigned short* xt   = (const unsigned short*)(ws + WS_XT);

  const int tid  = threadIdx.x;
  const int lane = tid & 63;
  const int wv   = tid >> 6;      // wave 0..3 -> m-tile
  const int fr   = lane & 15;     // MFMA frag row (m for A, n for B)
  const int fg   = lane >> 4;     // k-group 0..3
  const int mh   = blockIdx.x & 1;
  const int nsl  = blockIdx.x >> 1;
  const int hc0  = nsl << 3;
  const int m0   = mh << 6;
  const int grp  = mh;

  // ---- stage this block's weight slice into LDS (once) ----
  for (int lr = 0; lr < 32; ++lr) {
    int grow = (lr >> 3) * HDIM + hc0 + (lr & 7);   // gate*H + hcol
    ((ushort4*)(sWhi + lr*SMEM_WHI_ROW))[tid] =
        ((const ushort4*)(whhi + (size_t)grow*HDIM))[tid];
    ((ushort4*)(sWlo + lr*SMEM_WLO_ROW))[tid] =
        ((const ushort4*)(whlo + (size_t)grow*HDIM))[tid];
    if (tid < 64)
      ((ushort4*)(sWhi + lr*SMEM_WHI_ROW + 1024))[tid] =
          ((const ushort4*)(wxhi + (size_t)grow*DDIM))[tid];
  }
  __syncthreads();

  // update-phase mapping: thread -> (row umr, col-pair 2*ujp, 2*ujp+1); u32-packed h store
  const int ujp = tid & 3;
  const int umr = tid >> 2;        // 0..63
  const float bge = bx[0*HDIM + hc0 + 2*ujp], bgo = bx[0*HDIM + hc0 + 2*ujp + 1];
  const float bie = bx[1*HDIM + hc0 + 2*ujp], bio = bx[1*HDIM + hc0 + 2*ujp + 1];
  const float bfe = bx[2*HDIM + hc0 + 2*ujp], bfo = bx[2*HDIM + hc0 + 2*ujp + 1];
  const float boe = bx[3*HDIM + hc0 + 2*ujp], boo = bx[3*HDIM + hc0 + 2*ujp + 1];

  float ce = 0.f, co = 0.f;
  const int arow = m0 + wv*16 + fr;   // global batch row for this lane's A-frags

  // wave-parallel barrier poll plumbing: lane j<128 watches group member j
  const unsigned* mystamp = (tid < 128)
      ? stamp + ((((unsigned)tid << 1) | (unsigned)grp) * 16) : stamp;

  for (int t = 0; t < TSTEPS; ++t) {
    f32x4 a0h = {0.f,0.f,0.f,0.f}, a1h = {0.f,0.f,0.f,0.f};
    f32x4 a0l = {0.f,0.f,0.f,0.f}, a1l = {0.f,0.f,0.f,0.f};

    // ---- x-path (independent of h_t: overlaps other blocks' tails) ----
    {
      const unsigned short* xrow = xt + ((size_t)t*BDIM + arow)*DDIM + fg*8;
      #pragma unroll
      for (int kc = 0; kc < 8; kc += 2) {
        frag8 ax0 = *(const frag8*)(xrow + kc*32);
        frag8 ax1 = *(const frag8*)(xrow + (kc+1)*32);
        frag8 b00 = *(const frag8*)(sWhi + fr*SMEM_WHI_ROW      + 1024 + kc*32 + fg*8);
        frag8 b10 = *(const frag8*)(sWhi + (16+fr)*SMEM_WHI_ROW + 1024 + kc*32 + fg*8);
        frag8 b01 = *(const frag8*)(sWhi + fr*SMEM_WHI_ROW      + 1024 + (kc+1)*32 + fg*8);
        frag8 b11 = *(const frag8*)(sWhi + (16+fr)*SMEM_WHI_ROW + 1024 + (kc+1)*32 + fg*8);
        a0h = __builtin_amdgcn_mfma_f32_16x16x32_bf16(ax0, b00, a0h, 0, 0, 0);
        a1h = __builtin_amdgcn_mfma_f32_16x16x32_bf16(ax0, b10, a1h, 0, 0, 0);
        a0l = __builtin_amdgcn_mfma_f32_16x16x32_bf16(ax1, b01, a0l, 0, 0, 0);
        a1l = __builtin_amdgcn_mfma_f32_16x16x32_bf16(ax1, b11, a1l, 0, 0, 0);
      }
    }

    // ---- wait: all 128 same-group stamps >= t (t=0 trivially true) ----
    if (tid < 128) {
      while (ld_agent_u32(mystamp) < (unsigned)t)
        __builtin_amdgcn_s_sleep(1);
    }
    __syncthreads();

    // ---- h-path: gates += h_t @ (Wh_hi + Wh_lo)^T; h via sc1 u64 loads (LLC-fresh) ----
    {
      const unsigned long long* hq =
          (const unsigned long long*)(hbuf + ((size_t)(t & 1)*BDIM + arow)*HDIM + fg*8);
      #pragma unroll 8
      for (int kc = 0; kc < 32; ++kc) {
        union { unsigned long long q[2]; frag8 f; } ua;
        ua.q[0] = ld_agent_u64(hq + kc*8);
        ua.q[1] = ld_agent_u64(hq + kc*8 + 1);
        frag8 a   = ua.f;
        frag8 bh0 = *(const frag8*)(sWhi + fr*SMEM_WHI_ROW      + kc*32 + fg*8);
        frag8 bh1 = *(const frag8*)(sWhi + (16+fr)*SMEM_WHI_ROW + kc*32 + fg*8);
        frag8 bl0 = *(const frag8*)(sWlo + fr*SMEM_WLO_ROW      + kc*32 + fg*8);
        frag8 bl1 = *(const frag8*)(sWlo + (16+fr)*SMEM_WLO_ROW + kc*32 + fg*8);
        a0h = __builtin_amdgcn_mfma_f32_16x16x32_bf16(a, bh0, a0h, 0, 0, 0);
        a1h = __builtin_amdgcn_mfma_f32_16x16x32_bf16(a, bh1, a1h, 0, 0, 0);
        a0l = __builtin_amdgcn_mfma_f32_16x16x32_bf16(a, bl0, a0l, 0, 0, 0);
        a1l = __builtin_amdgcn_mfma_f32_16x16x32_bf16(a, bl1, a1l, 0, 0, 0);
      }
    }

    f32x4 acc0 = a0h + a0l;
    f32x4 acc1 = a1h + a1l;

    // ---- scatter accs to LDS (C/D layout: col=lane&15, row=(lane>>4)*4+reg) ----
    {
      int mb = wv*16 + fg*4;
      #pragma unroll
      for (int r = 0; r < 4; ++r) {
        sG[(mb + r)*33 + fr]      = acc0[r];
        sG[(mb + r)*33 + 16 + fr] = acc1[r];
      }
    }
    __syncthreads();

    // ---- gate nonlinearities + state update; u32-packed write-through h store ----
    {
      const float* gr = sG + umr*33;
      float gge = gr[ 0 + 2*ujp] + bge, ggo = gr[ 0 + 2*ujp + 1] + bgo;
      float gie = gr[ 8 + 2*ujp] + bie, gio = gr[ 8 + 2*ujp + 1] + bio;
      float gfe = gr[16 + 2*ujp] + bfe, gfo = gr[16 + 2*ujp + 1] + bfo;
      float goe = gr[24 + 2*ujp] + boe, goo = gr[24 + 2*ujp + 1] + boo;

      ce = tanh_f(gge)*sigm(gie) + ce*sigm(gfe);
      co = tanh_f(ggo)*sigm(gio) + co*sigm(gfo);
      float he = tanh_f(ce)*sigm(goe);
      float ho = tanh_f(co)*sigm(goo);

      unsigned hv = (unsigned)f2bf(he) | ((unsigned)f2bf(ho) << 16);
      unsigned* hw32 = (unsigned*)(hbuf + (size_t)((t + 1) & 1)*BDIM*HDIM
                                   + (size_t)(m0 + umr)*HDIM + hc0);
      st_agent_u32(hw32 + ujp, hv);
    }

    // ---- arrive: barrier drains vmcnt(0) (h at LLC), then publish stamp ----
    __syncthreads();
    if (tid == 0)
      st_agent_u32(stamp + (unsigned)blockIdx.x*16, (unsigned)(t + 1));
  }

  // ---- wait: own group finished all steps (h_T complete in hbuf slot 0) ----
  if (tid < 128) {
    while (ld_agent_u32(mystamp) < (unsigned)TSTEPS)
      __builtin_amdgcn_s_sleep(1);
  }
  __syncthreads();

  // ---- stage h_T rows [m0, m0+64) (bf16, slot 0) into LDS (weights dead; reuse smem) ----
  // 64 rows x 1024 u16 = 16384 u64; one row = 256 u64 -> row = q>>8, off = q&255.
  // (R4 bug: q>>7/&127 scrambled rows and left bytes [1024,2048) of each sH row stale ->
  //  stale fp32 LDS bits decoded as bf16 NaN -> projection NaN. Fixed here.)
  {
    unsigned short* sH = (unsigned short*)smem;      // [64][1032]
    const unsigned long long* hsrc = (const unsigned long long*)(hbuf + (size_t)m0*HDIM);
    #pragma unroll 4
    for (int i = 0; i < 64; ++i) {
      int q = i*256 + tid;          // 16384 u64 total
      int row = q >> 8, off = q & 255;
      unsigned long long v = ld_agent_u64(hsrc + q);
      ((unsigned long long*)(sH + row*SMEM_H_ROW))[off] = v;
    }
  }
  __syncthreads();

  // ---- projection: p = h_T @ Wp^T + bp (bf16 h from LDS, fp32 accumulate) ----
  {
    const unsigned short* sH = (const unsigned short*)smem;
    #pragma unroll
    for (int it = 0; it < 2; ++it) {
      int ml = (tid >> 3) + it*32;
      int n  = hc0 + (tid & 7);
      const unsigned short* hr = sH + ml*SMEM_H_ROW;
      const float4* wr = (const float4*)(Wp + (size_t)n*HDIM);
      float s = 0.f;
      #pragma unroll 4
      for (int k = 0; k < 128; ++k) {
        const ushort4* hp = (const ushort4*)(hr + k*8);
        ushort4 ha = hp[0], hb = hp[1];
        float4 wa = wr[2*k], wb = wr[2*k + 1];
        s += bf2f(ha.x)*wa.x + bf2f(ha.y)*wa.y + bf2f(ha.z)*wa.z + bf2f(ha.w)*wa.w;
        s += bf2f(hb.x)*wb.x + bf2f(hb.y)*wb.y + bf2f(hb.z)*wb.z + bf2f(hb.w)*wb.w;
      }
      st_agent_f32(&pbuf[(size_t)(m0 + ml)*ODIM + n], s + bp[n]);
    }
  }
  __syncthreads();
  if (tid == 0)
    st_agent_u32(stamp + (unsigned)blockIdx.x*16, (unsigned)(TSTEPS + 1));

  if (blockIdx.x >= BDIM) return;

  // ---- wait: all 256 blocks' projections done (256 lanes poll 256 slots) ----
  {
    const unsigned* sp = stamp + (unsigned)tid*16;
    while (ld_agent_u32(sp) < (unsigned)(TSTEPS + 1))
      __builtin_amdgcn_s_sleep(1);
  }
  __syncthreads();

  // ---- softmax: one block per batch row (pbuf via sc1 u64 loads) ----
  {
    float* sRed = (float*)(smem + 64*SMEM_H_ROW*2);   // past sH
    int b = blockIdx.x;
    const unsigned long long* pr = (const unsigned long long*)(pbuf + (size_t)b*ODIM);
    union { unsigned long long q; float f[2]; } u0, u1;
    u0.q = ld_agent_u64(pr + 2*tid);
    u1.q = ld_agent_u64(pr + 2*tid + 1);
    float4 v; v.x = u0.f[0]; v.y = u0.f[1]; v.z = u1.f[0]; v.w = u1.f[1];
    float mx = fmaxf(fmaxf(v.x, v.y), fmaxf(v.z, v.w));
    #pragma unroll
    for (int off = 32; off > 0; off >>= 1)
      mx = fmaxf(mx, __shfl_xor(mx, off, 64));
    if (lane == 0) sRed[wv] = mx;
    __syncthreads();
    mx = fmaxf(fmaxf(sRed[0], sRed[1]), fmaxf(sRed[2], sRed[3]));
    float e0 = __expf(v.x - mx), e1 = __expf(v.y - mx),
          e2 = __expf(v.z - mx), e3 = __expf(v.w - mx);
    float s = e0 + e1 + e2 + e3;
    #pragma unroll
    for (int off = 32; off > 0; off >>= 1)
      s += __shfl_xor(s, off, 64);
    if (lane == 0) sRed[8 + wv] = s;
    __syncthreads();
    s = sRed[8] + sRed[9] + sRed[10] + sRed[11];
    float inv = 1.f / s;
    float4 o; o.x = e0*inv; o.y = e1*inv; o.z = e2*inv; o.w = e3*inv;
    ((float4*)(out + (size_t)b*ODIM))[tid] = o;
  }
}

// ---------------- host launch ----------------
extern "C" void kernel_launch(void* const* d_in, const int* in_sizes, int n_in,
                              void* d_out, int out_size, void* d_ws, size_t ws_size,
                              hipStream_t stream) {
  (void)in_sizes; (void)n_in; (void)out_size; (void)ws_size;
  const float* x  = (const float*)d_in[0];
  const float* Wx = (const float*)d_in[1];
  const float* bx = (const float*)d_in[2];
  const float* Wh = (const float*)d_in[3];
  const float* Wp = (const float*)d_in[4];
  const float* bp = (const float*)d_in[5];
  float* out = (float*)d_out;
  unsigned char* ws = (unsigned char*)d_ws;

  // zero stamps + h0 double-buffer slot 0
  hipMemsetAsync(ws, 0, WS_HBUF + BDIM*HDIM*2, stream);

  hipLaunchKernelGGL(prep_kernel, dim3(1024), dim3(256), 0, stream, Wh, Wx, x, ws);

  hipFuncSetAttribute(reinterpret_cast<const void*>(&lstm_main),
                      hipFuncAttributeMaxDynamicSharedMemorySize, SMEM_BYTES);
  void* args[5];
  args[0] = (void*)&bx; args[1] = (void*)&Wp; args[2] = (void*)&bp;
  args[3] = (void*)&ws; args[4] = (void*)&out;
  hipLaunchCooperativeKernel(reinterpret_cast<const void*>(&lstm_main),
                             dim3(256), dim3(256), args, SMEM_BYTES, stream);
}